// Round 2
// baseline (317.181 us; speedup 1.0000x reference)
//
#include <hip/hip_runtime.h>

#define NJ     55
#define BLK    64                    // one wave per block: wave-autonomous, no barriers
#define SLABF  (BLK * NJ)            // 3520 floats per 64-vertex weight slab
#define SLABB  (SLABF * 4)           // 14080 bytes
#define NF16   13                    // 13 full-wave 16B/lane chunks = 13312 B
#define NF4    3                     // 3 full-wave 4B/lane chunks  =   768 B
#define NSTAGE (NF16 + NF4)          // 16 global_load_lds ops per slab
#define GRID_BLOCKS 1280             // 5 resident blocks/CU (2x14080B LDS) x 256 CU

static_assert(NF16 * 1024 + NF4 * 256 == SLABB, "staging chunks must tile the slab exactly");
static_assert(NSTAGE == 16, "vmcnt(16) literal below must equal NSTAGE");

// async global->LDS: LDS dest = wave-uniform base + lane*W (HW-generated),
// global src is per-lane. No VGPR round-trip; tracked by vmcnt.
// ALL chunks are full-wave (no exec-masked staging): the HW lane->LDS scatter
// is only measured/verified for full waves, and a masked 16B chunk would risk
// an out-of-bounds LDS write if inactive lanes still scatter.
#define GLOAD_LDS(g, l, W)                                              \
    __builtin_amdgcn_global_load_lds(                                   \
        (const __attribute__((address_space(1))) void*)(g),             \
        (__attribute__((address_space(3))) void*)(l), W, 0, 0)

__device__ __forceinline__ void stage_slab(const float* __restrict__ gsrc,
                                           float* lbase, int lane)
{
    #pragma unroll
    for (int i = 0; i < NF16; ++i)                       // 13 x 1024 B
        GLOAD_LDS(gsrc + i * 256 + lane * 4, lbase + i * 256, 16);
    #pragma unroll
    for (int k = 0; k < NF4; ++k)                        // 3 x 256 B tail
        GLOAD_LDS(gsrc + NF16 * 256 + k * 64 + lane,
                  lbase + NF16 * 256 + k * 64, 4);
}

// Persistent wave-private double-buffered LBS:
//  - 1280 blocks (5/CU, LDS-limited) each walk slabs s, s+1280, s+2560, ...
//  - per iteration: issue point loads, issue 16 async global_load_lds for the
//    NEXT slab, then s_waitcnt vmcnt(16): the CURRENT buffer is complete while
//    the next slab's 16 loads stay in flight under the whole compute phase.
//    -> every wave keeps ~14 KB outstanding ~always (70 KB/CU >> BW*latency),
//    vs. the old stage -> full-drain -> compute duty cycle (~72% of stream BW).
//  - one wave per block: vmcnt is wave-private, no __syncthreads anywhere.
__global__ __launch_bounds__(BLK) void lbs_kernel(
    const float* __restrict__ points,
    const float* __restrict__ weights,
    const float* __restrict__ se3,
    float* __restrict__ out,
    int n_verts)
{
    __shared__ __align__(16) float s_w[2 * SLABF];   // 28160 B double buffer, exact fit

    const int lane   = threadIdx.x;
    const int nslab  = n_verts / BLK;                // full slabs
    const int stride = gridDim.x;
    const float4* M  = (const float4*)se3;           // uniform addr -> s_load/K$

    int s = blockIdx.x;
    if (s < nslab) {
        stage_slab(weights + (size_t)s * SLABF, s_w, lane);
        int cur = 0;
        while (true) {
            const int n = s * BLK + lane;
            // Point loads issued BEFORE the next-slab stage: the counted
            // vmcnt(16) below then also retires them, so the compiler's own
            // dependency wait for px/py/pz never needs vmcnt(0)
            // (a vmcnt(0) here would drain the prefetch and kill the pipe).
            const float px = points[n * 3 + 0];
            const float py = points[n * 3 + 1];
            const float pz = points[n * 3 + 2];
            __builtin_amdgcn_sched_barrier(0);

            const int snext = s + stride;
            if (snext < nslab) {
                stage_slab(weights + (size_t)snext * SLABF,
                           s_w + (cur ^ 1) * SLABF, lane);
                asm volatile("s_waitcnt vmcnt(16)" ::: "memory");  // cur buf ready,
            } else {                                               // 16 newest in flight
                asm volatile("s_waitcnt vmcnt(0)" ::: "memory");   // last slab: drain
            }
            __builtin_amdgcn_sched_barrier(0);

            // weights row from LDS, stride 55 floats: bank = 23*lane mod 32,
            // 23 odd -> bijective over 32 lanes -> only the free 2-way wave64
            // aliasing. Conflict-free.
            const float* wr = s_w + cur * SLABF + lane * NJ;
            float a[12];
            #pragma unroll
            for (int e = 0; e < 12; ++e) a[e] = 0.f;
            #pragma unroll 5
            for (int j = 0; j < NJ; ++j) {
                const float w  = wr[j];
                const float4 r0 = M[j * 4 + 0];
                const float4 r1 = M[j * 4 + 1];
                const float4 r2 = M[j * 4 + 2];   // row 3 of each SE3 unused
                a[0] += w*r0.x; a[1] += w*r0.y; a[2]  += w*r0.z; a[3]  += w*r0.w;
                a[4] += w*r1.x; a[5] += w*r1.y; a[6]  += w*r1.z; a[7]  += w*r1.w;
                a[8] += w*r2.x; a[9] += w*r2.y; a[10] += w*r2.z; a[11] += w*r2.w;
            }
            out[n * 3 + 0] = a[0]*px + a[1]*py + a[2] *pz + a[3];
            out[n * 3 + 1] = a[4]*px + a[5]*py + a[6] *pz + a[7];
            out[n * 3 + 2] = a[8]*px + a[9]*py + a[10]*pz + a[11];

            if (snext >= nslab) break;
            s = snext;
            cur ^= 1;
        }
    }

    // ragged tail (n_verts % 64 != 0) — direct from global, block 0 only.
    // (1e6 % 64 == 0, so this is dead for the bench shape; kept for correctness.)
    const int rem = n_verts - nslab * BLK;
    if (rem && blockIdx.x == 0 && lane < rem) {
        const int n = nslab * BLK + lane;
        const float* wr = weights + (size_t)n * NJ;
        float a[12];
        #pragma unroll
        for (int e = 0; e < 12; ++e) a[e] = 0.f;
        for (int j = 0; j < NJ; ++j) {
            const float w  = wr[j];
            const float4 r0 = M[j * 4 + 0];
            const float4 r1 = M[j * 4 + 1];
            const float4 r2 = M[j * 4 + 2];
            a[0] += w*r0.x; a[1] += w*r0.y; a[2]  += w*r0.z; a[3]  += w*r0.w;
            a[4] += w*r1.x; a[5] += w*r1.y; a[6]  += w*r1.z; a[7]  += w*r1.w;
            a[8] += w*r2.x; a[9] += w*r2.y; a[10] += w*r2.z; a[11] += w*r2.w;
        }
        const float px = points[n * 3 + 0];
        const float py = points[n * 3 + 1];
        const float pz = points[n * 3 + 2];
        out[n * 3 + 0] = a[0]*px + a[1]*py + a[2] *pz + a[3];
        out[n * 3 + 1] = a[4]*px + a[5]*py + a[6] *pz + a[7];
        out[n * 3 + 2] = a[8]*px + a[9]*py + a[10]*pz + a[11];
    }
}

extern "C" void kernel_launch(void* const* d_in, const int* in_sizes, int n_in,
                              void* d_out, int out_size, void* d_ws, size_t ws_size,
                              hipStream_t stream)
{
    const float* points  = (const float*)d_in[0];
    const float* weights = (const float*)d_in[1];
    const float* se3     = (const float*)d_in[2];
    float* out = (float*)d_out;

    const int n_verts = in_sizes[0] / 3;          // points is (N,3) fp32
    const int nslab   = n_verts / BLK;
    int grid = GRID_BLOCKS;
    if (grid > nslab) grid = (nslab > 0) ? nslab : 1;
    lbs_kernel<<<grid, BLK, 0, stream>>>(points, weights, se3, out, n_verts);
}